// Round 7
// baseline (171.001 us; speedup 1.0000x reference)
//
#include <hip/hip_runtime.h>
#include <hip/hip_bf16.h>
#include <stdint.h>

// Problem constants (from reference)
#define N_NODES_C 100000
#define N_EDGES_C 600000
#define H_C 128

// MFMA fragment types: 32x32x16 bf16 -> A/B = 8 bf16 (4 VGPR), C/D = 16 f32
typedef __bf16 bf16x8 __attribute__((ext_vector_type(8)));
typedef float f32x16 __attribute__((ext_vector_type(16)));
typedef float f32x4v __attribute__((ext_vector_type(4)));
typedef _Float16 half8 __attribute__((ext_vector_type(8)));
typedef unsigned short ushort8 __attribute__((ext_vector_type(8)));

// fp32 -> bf16 round-to-nearest-even
__device__ __forceinline__ unsigned short f2bf(float f) {
    unsigned int u = __builtin_bit_cast(unsigned int, f);
    u += 0x7fffu + ((u >> 16) & 1u);
    return (unsigned short)(u >> 16);
}

// Kernel 1: node GEMM with in-register W1 formatting (no separate w1fmt pass).
//  uv[0:N*128)  = u' = z @ W1[:128] + b1 (fp16)
//  uv[N*128: )  = v  = z @ W1[128:]      (fp16)
// Block = 4 waves; wave wv owns N-subtiles {2wv, 2wv+1} of the combined
// N=256 output; holds its 16 B-fragments in registers (built once from W1,
// L2-hot). Grid-stride over 32-node tiles; 16 A-loads issued upfront.
__launch_bounds__(256, 2)
__global__ void node_gemm_kernel(const float* __restrict__ z,
                                 const float* __restrict__ W1,
                                 const float* __restrict__ b1,
                                 _Float16* __restrict__ uv) {
    const int lane = threadIdx.x & 63;
    const int wv   = threadIdx.x >> 6;      // wave 0..3
    const int l31  = lane & 31;
    const int half = lane >> 5;
    const int uh   = wv >> 1;               // 0 = u half (b1), 1 = v half

    // ---- Phase 0: build this wave's 16 B-fragments from W1 ----
    // Fragment (s,t): lane L holds Bc[k = s*16 + (L>>5)*8 + j][n2], j=0..7,
    // n2 = (2wv+t)*32 + (L&31);  Bc[k][n2] = n2<128 ? W1[k][n2]
    //                                               : W1[128+k][n2-128].
    bf16x8 bfrag[8][2];
    float  badd[2];
    int    ncol[2];
    #pragma unroll
    for (int t = 0; t < 2; ++t) {
        int n2  = (wv * 2 + t) * 32 + l31;          // global column 0..255
        ncol[t] = n2 - uh * 128;                    // column within u/v half
        badd[t] = uh ? 0.0f : b1[n2];
        const float* wcol = W1 + (size_t)(uh ? 128 : 0) * H_C + ncol[t];
        #pragma unroll
        for (int s = 0; s < 8; ++s) {
            ushort8 au;
            #pragma unroll
            for (int j = 0; j < 8; ++j) {
                int k = s * 16 + half * 8 + j;      // 0..127
                au[j] = f2bf(wcol[(size_t)k * H_C]);
            }
            bfrag[s][t] = __builtin_bit_cast(bf16x8, au);
        }
    }
    const size_t segbase = uh ? (size_t)N_NODES_C * H_C : 0;

    // ---- Phase 1: node GEMM, grid-stride over 32-node tiles ----
    for (int tile = blockIdx.x; tile < N_NODES_C / 32; tile += gridDim.x) {
        const float* arow = z + (size_t)(tile * 32 + l31) * H_C + half * 8;

        // Issue ALL A-loads for this tile before any dependent use.
        f32x4v alo[8], ahi[8];
        #pragma unroll
        for (int s = 0; s < 8; ++s) {
            alo[s] = *reinterpret_cast<const f32x4v*>(arow + s * 16);
            ahi[s] = *reinterpret_cast<const f32x4v*>(arow + s * 16 + 4);
        }

        f32x16 acc[2] = {};
        #pragma unroll
        for (int s = 0; s < 8; ++s) {
            ushort8 au;
            #pragma unroll
            for (int j = 0; j < 4; ++j) {
                au[j]     = f2bf(alo[s][j]);
                au[j + 4] = f2bf(ahi[s][j]);
            }
            bf16x8 a = __builtin_bit_cast(bf16x8, au);
            acc[0] = __builtin_amdgcn_mfma_f32_32x32x16_bf16(a, bfrag[s][0], acc[0], 0, 0, 0);
            acc[1] = __builtin_amdgcn_mfma_f32_32x32x16_bf16(a, bfrag[s][1], acc[1], 0, 0, 0);
        }

        // Epilogue: +b1 (u half), fp16 pack via lane-pair shuffle, dword store.
        const int node0 = tile * 32;
        #pragma unroll
        for (int t = 0; t < 2; ++t) {
            #pragma unroll
            for (int r = 0; r < 16; ++r) {
                int row = (r & 3) + 8 * (r >> 2) + 4 * half;    // C/D row map
                float v = acc[t][r] + badd[t];
                float fo = __shfl_xor(v, 1);
                if ((lane & 1) == 0) {
                    unsigned int pk = __builtin_bit_cast(
                        unsigned int, __builtin_amdgcn_cvt_pkrtz(v, fo));
                    size_t idx = segbase + (size_t)(node0 + row) * H_C + ncol[t];
                    *reinterpret_cast<unsigned int*>(uv + idx) = pk;
                }
            }
        }
    }
}

// Kernel 2: edge phase. Quarter-wave (16 lanes) per EIGHT consecutive edges:
// indices via four broadcast int4 loads; 16 row-gathers (16 B/lane) in
// flight; per-edge dot with W2 slice; xor-shuffle reduce; lane 0 stores
// two float4s.
__global__ void edge_kernel(const _Float16* __restrict__ uv,
                            const int* __restrict__ ei,
                            const float* __restrict__ w2,
                            const float* __restrict__ b2,
                            float* __restrict__ out) {
    const int tid = blockIdx.x * blockDim.x + threadIdx.x;
    const int j   = tid & 15;                       // lane within quarter
    const int q   = tid >> 4;                       // quarter id
    const int e0  = q * 8;
    if (e0 >= N_EDGES_C) return;

    float w2v[8];
    {
        f32x4v a = *reinterpret_cast<const f32x4v*>(w2 + j * 8);
        f32x4v b = *reinterpret_cast<const f32x4v*>(w2 + j * 8 + 4);
        #pragma unroll
        for (int k = 0; k < 4; ++k) { w2v[k] = a[k]; w2v[k + 4] = b[k]; }
    }
    const float c2 = b2[0];
    const _Float16* vbase = uv + (size_t)N_NODES_C * H_C;

    int4 sa = *reinterpret_cast<const int4*>(ei + e0);
    int4 sb = *reinterpret_cast<const int4*>(ei + e0 + 4);
    int4 da = *reinterpret_cast<const int4*>(ei + N_EDGES_C + e0);
    int4 db = *reinterpret_cast<const int4*>(ei + N_EDGES_C + e0 + 4);

    int se[8] = { sa.x, sa.y, sa.z, sa.w, sb.x, sb.y, sb.z, sb.w };
    int de[8] = { da.x, da.y, da.z, da.w, db.x, db.y, db.z, db.w };

    half8 uu[8], vv[8];
    #pragma unroll
    for (int i = 0; i < 8; ++i) {
        uu[i] = *reinterpret_cast<const half8*>(uv    + (size_t)se[i] * H_C + j * 8);
        vv[i] = *reinterpret_cast<const half8*>(vbase + (size_t)de[i] * H_C + j * 8);
    }

    float p[8];
    #pragma unroll
    for (int i = 0; i < 8; ++i) {
        float acc = 0.0f;
        #pragma unroll
        for (int k = 0; k < 8; ++k) {
            float h = (float)uu[i][k] + (float)vv[i][k];
            h = h > 0.0f ? h : 0.0f;
            acc = fmaf(h, w2v[k], acc);
        }
        p[i] = acc;
    }
    #pragma unroll
    for (int m = 1; m <= 8; m <<= 1) {
        #pragma unroll
        for (int i = 0; i < 8; ++i) p[i] += __shfl_xor(p[i], m);
    }
    if (j == 0) {
        float4 o0 = { p[0] + c2, p[1] + c2, p[2] + c2, p[3] + c2 };
        float4 o1 = { p[4] + c2, p[5] + c2, p[6] + c2, p[7] + c2 };
        *reinterpret_cast<float4*>(out + e0)     = o0;
        *reinterpret_cast<float4*>(out + e0 + 4) = o1;
    }
}

extern "C" void kernel_launch(void* const* d_in, const int* in_sizes, int n_in,
                              void* d_out, int out_size, void* d_ws, size_t ws_size,
                              hipStream_t stream) {
    const float* z  = (const float*)d_in[0];
    const int*   ei = (const int*)d_in[1];
    const float* W1 = (const float*)d_in[2];
    const float* b1 = (const float*)d_in[3];
    const float* W2 = (const float*)d_in[4];
    const float* b2 = (const float*)d_in[5];
    float* out = (float*)d_out;

    // Workspace: uv = u' then v, 2 * 100000*128 fp16 = 51.2 MB
    _Float16* uv = (_Float16*)d_ws;

    node_gemm_kernel<<<1024, 256, 0, stream>>>(z, W1, b1, uv);

    int nquarters = N_EDGES_C / 8;       // 75000
    edge_kernel<<<(nquarters * 16 + 255) / 256, 256, 0, stream>>>(uv, ei, W2, b2, out);
}

// Round 8
// 149.785 us; speedup vs baseline: 1.1416x; 1.1416x over previous
//
#include <hip/hip_runtime.h>
#include <hip/hip_bf16.h>
#include <stdint.h>

// Problem constants (from reference)
#define N_NODES_C 100000
#define N_EDGES_C 600000
#define H_C 128

// MFMA fragment types: 32x32x16 bf16 -> A/B = 8 bf16 (4 VGPR), C/D = 16 f32
typedef __bf16 bf16x8 __attribute__((ext_vector_type(8)));
typedef float f32x16 __attribute__((ext_vector_type(16)));
typedef float f32x4v __attribute__((ext_vector_type(4)));
typedef _Float16 half8 __attribute__((ext_vector_type(8)));
typedef unsigned short ushort8 __attribute__((ext_vector_type(8)));

#define LDS_STRIDE 136   // bf16 elems per LDS row: 128 + 8 pad (16-B aligned)

// fp32 -> bf16 round-to-nearest-even
__device__ __forceinline__ unsigned short f2bf(float f) {
    unsigned int u = __builtin_bit_cast(unsigned int, f);
    u += 0x7fffu + ((u >> 16) & 1u);
    return (unsigned short)(u >> 16);
}

// Kernel 1: W1 fp32 [256,128] -> bf16 combined-B in MFMA B-fragment order.
// Bc[k][n2], k=0..127, n2=0..255:  n2<128 -> W1[k][n2] (u path),
//                                  n2>=128 -> W1[128+k][n2-128] (v path).
// Fragment (s = K-step 0..7, T = N-subtile 0..7): lane L holds
// Bc[k = s*16 + (L>>5)*8 + j][n2 = T*32 + (L&31)], j = 0..7 contiguous.
// Flat index: ((s*8 + T)*64 + L)*8 + j   (32768 elements, 64 KB)
__global__ void w1fmt_kernel(const float* __restrict__ W1,
                             unsigned short* __restrict__ w1f) {
    int i = blockIdx.x * blockDim.x + threadIdx.x;
    if (i >= 8 * 8 * 64 * 8) return;
    int j = i & 7;
    int L = (i >> 3) & 63;
    int t = (i >> 9) & 7;
    int s = (i >> 12) & 7;
    int k  = s * 16 + ((L >> 5) * 8) + j;   // 0..127
    int n2 = t * 32 + (L & 31);             // 0..255
    float w = (n2 < 128) ? W1[k * H_C + n2]
                         : W1[(128 + k) * H_C + (n2 - 128)];
    w1f[i] = f2bf(w);
}

// Kernel 2 (v3): node GEMM with LDS-staged A.
//  uv[0:N*128)  = u' = z @ W1[:128] + b1 (fp16)
//  uv[N*128: )  = v  = z @ W1[128:]      (fp16)
// One block = one 32-node tile. 256 threads coalesced-load the 16-KB z chunk
// (16 contiguous floats each), convert to bf16 once, stage in LDS (stride
// 136). Wave wv owns N-subtiles {2wv, 2wv+1}; B-fragments register-primed
// from w1f. MFMA loop is pure ds_read_b128 + MFMA.
__launch_bounds__(256, 2)
__global__ void node_gemm_kernel(const float* __restrict__ z,
                                 const unsigned short* __restrict__ w1f,
                                 const float* __restrict__ b1,
                                 _Float16* __restrict__ uv) {
    __shared__ unsigned short smem[32 * LDS_STRIDE];   // 8704 B

    const int lane = threadIdx.x & 63;
    const int wv   = threadIdx.x >> 6;      // wave 0..3
    const int l31  = lane & 31;
    const int half = lane >> 5;
    const int uh   = wv >> 1;               // 0 = u half (b1), 1 = v half
    const int tile = blockIdx.x;            // 32-node tile, one per block

    // ---- Stage A: coalesced global read -> bf16 -> LDS ----
    {
        const int sr = threadIdx.x >> 3;          // row 0..31
        const int sc = (threadIdx.x & 7) * 16;    // col 0,16,...,112
        const float* src = z + (size_t)(tile * 32 + sr) * H_C + sc;
        f32x4v f0 = *reinterpret_cast<const f32x4v*>(src);
        f32x4v f1 = *reinterpret_cast<const f32x4v*>(src + 4);
        f32x4v f2 = *reinterpret_cast<const f32x4v*>(src + 8);
        f32x4v f3 = *reinterpret_cast<const f32x4v*>(src + 12);
        ushort8 lo, hi;
        #pragma unroll
        for (int j = 0; j < 4; ++j) {
            lo[j]     = f2bf(f0[j]);
            lo[j + 4] = f2bf(f1[j]);
            hi[j]     = f2bf(f2[j]);
            hi[j + 4] = f2bf(f3[j]);
        }
        *reinterpret_cast<ushort8*>(smem + sr * LDS_STRIDE + sc)     = lo;
        *reinterpret_cast<ushort8*>(smem + sr * LDS_STRIDE + sc + 8) = hi;
    }

    // ---- Prime B fragments from w1f (coalesced, L2-hot) ----
    bf16x8 bfrag[8][2];
    #pragma unroll
    for (int s = 0; s < 8; ++s) {
        #pragma unroll
        for (int t = 0; t < 2; ++t) {
            bfrag[s][t] = reinterpret_cast<const bf16x8*>(w1f)
                              [(s * 8 + wv * 2 + t) * 64 + lane];
        }
    }

    float badd[2];
    int   ncol[2];
    #pragma unroll
    for (int t = 0; t < 2; ++t) {
        int n2  = (wv * 2 + t) * 32 + l31;  // global column 0..255
        ncol[t] = n2 - uh * 128;            // column within u/v half
        badd[t] = uh ? 0.0f : b1[n2];
    }
    const size_t segbase = uh ? (size_t)N_NODES_C * H_C : 0;

    __syncthreads();

    // ---- MFMA loop: A from LDS (m = l31, k = s*16 + half*8 + j) ----
    f32x16 acc[2] = {};
    #pragma unroll
    for (int s = 0; s < 8; ++s) {
        bf16x8 a = *reinterpret_cast<const bf16x8*>(
                       smem + l31 * LDS_STRIDE + s * 16 + half * 8);
        acc[0] = __builtin_amdgcn_mfma_f32_32x32x16_bf16(a, bfrag[s][0], acc[0], 0, 0, 0);
        acc[1] = __builtin_amdgcn_mfma_f32_32x32x16_bf16(a, bfrag[s][1], acc[1], 0, 0, 0);
    }

    // ---- Epilogue: +b1 (u half), fp16 pack via lane-pair shuffle, store ----
    const int node0 = tile * 32;
    #pragma unroll
    for (int t = 0; t < 2; ++t) {
        #pragma unroll
        for (int r = 0; r < 16; ++r) {
            int row = (r & 3) + 8 * (r >> 2) + 4 * half;    // C/D row map
            float v = acc[t][r] + badd[t];
            float fo = __shfl_xor(v, 1);
            if ((lane & 1) == 0) {
                unsigned int pk = __builtin_bit_cast(
                    unsigned int, __builtin_amdgcn_cvt_pkrtz(v, fo));
                size_t idx = segbase + (size_t)(node0 + row) * H_C + ncol[t];
                *reinterpret_cast<unsigned int*>(uv + idx) = pk;
            }
        }
    }
}

// Kernel 3: edge phase. Quarter-wave (16 lanes) per EIGHT consecutive edges:
// indices via four broadcast int4 loads; 16 row-gathers (16 B/lane) in
// flight; per-edge dot with W2 slice; xor-shuffle reduce; lane 0 stores
// two float4s.
__global__ void edge_kernel(const _Float16* __restrict__ uv,
                            const int* __restrict__ ei,
                            const float* __restrict__ w2,
                            const float* __restrict__ b2,
                            float* __restrict__ out) {
    const int tid = blockIdx.x * blockDim.x + threadIdx.x;
    const int j   = tid & 15;                       // lane within quarter
    const int q   = tid >> 4;                       // quarter id
    const int e0  = q * 8;
    if (e0 >= N_EDGES_C) return;

    float w2v[8];
    {
        f32x4v a = *reinterpret_cast<const f32x4v*>(w2 + j * 8);
        f32x4v b = *reinterpret_cast<const f32x4v*>(w2 + j * 8 + 4);
        #pragma unroll
        for (int k = 0; k < 4; ++k) { w2v[k] = a[k]; w2v[k + 4] = b[k]; }
    }
    const float c2 = b2[0];
    const _Float16* vbase = uv + (size_t)N_NODES_C * H_C;

    int4 sa = *reinterpret_cast<const int4*>(ei + e0);
    int4 sb = *reinterpret_cast<const int4*>(ei + e0 + 4);
    int4 da = *reinterpret_cast<const int4*>(ei + N_EDGES_C + e0);
    int4 db = *reinterpret_cast<const int4*>(ei + N_EDGES_C + e0 + 4);

    int se[8] = { sa.x, sa.y, sa.z, sa.w, sb.x, sb.y, sb.z, sb.w };
    int de[8] = { da.x, da.y, da.z, da.w, db.x, db.y, db.z, db.w };

    half8 uu[8], vv[8];
    #pragma unroll
    for (int i = 0; i < 8; ++i) {
        uu[i] = *reinterpret_cast<const half8*>(uv    + (size_t)se[i] * H_C + j * 8);
        vv[i] = *reinterpret_cast<const half8*>(vbase + (size_t)de[i] * H_C + j * 8);
    }

    float p[8];
    #pragma unroll
    for (int i = 0; i < 8; ++i) {
        float acc = 0.0f;
        #pragma unroll
        for (int k = 0; k < 8; ++k) {
            float h = (float)uu[i][k] + (float)vv[i][k];
            h = h > 0.0f ? h : 0.0f;
            acc = fmaf(h, w2v[k], acc);
        }
        p[i] = acc;
    }
    #pragma unroll
    for (int m = 1; m <= 8; m <<= 1) {
        #pragma unroll
        for (int i = 0; i < 8; ++i) p[i] += __shfl_xor(p[i], m);
    }
    if (j == 0) {
        float4 o0 = { p[0] + c2, p[1] + c2, p[2] + c2, p[3] + c2 };
        float4 o1 = { p[4] + c2, p[5] + c2, p[6] + c2, p[7] + c2 };
        *reinterpret_cast<float4*>(out + e0)     = o0;
        *reinterpret_cast<float4*>(out + e0 + 4) = o1;
    }
}

extern "C" void kernel_launch(void* const* d_in, const int* in_sizes, int n_in,
                              void* d_out, int out_size, void* d_ws, size_t ws_size,
                              hipStream_t stream) {
    const float* z  = (const float*)d_in[0];
    const int*   ei = (const int*)d_in[1];
    const float* W1 = (const float*)d_in[2];
    const float* b1 = (const float*)d_in[3];
    const float* W2 = (const float*)d_in[4];
    const float* b2 = (const float*)d_in[5];
    float* out = (float*)d_out;

    // Workspace: [w1f: 64 KB][uv: u' then v, 2 * 100000*128 fp16 = 51.2 MB]
    unsigned short* w1f = (unsigned short*)d_ws;
    _Float16* uv = (_Float16*)((char*)d_ws + 65536);

    w1fmt_kernel<<<(8 * 8 * 64 * 8 + 255) / 256, 256, 0, stream>>>(W1, w1f);

    node_gemm_kernel<<<N_NODES_C / 32, 256, 0, stream>>>(z, w1f, b1, uv);

    int nquarters = N_EDGES_C / 8;       // 75000
    edge_kernel<<<(nquarters * 16 + 255) / 256, 256, 0, stream>>>(uv, ei, W2, b2, out);
}